// Round 18
// baseline (431.282 us; speedup 1.0000x reference)
//
#include <hip/hip_runtime.h>
#include <math.h>

// ---------------------------------------------------------------------------
// SheafDiffusion on MI355X — round 29: pipelined embed staging.
// Round-16 (430.7us, absmax 0.15625 exact): chunked-K raised occupancy
// 24.5->30% but k_embed_hm stayed ~53us -- mixed latency-bound (VALU 30%,
// LDS 33%, HBM 12%), and the chunk barriers serialize global-x latency.
// This round (numerics-INVARIANT, same k-ascending FMA chains):
//  1) register prefetch: chunk-1 x loads issue before the barrier, hiding
//     HBM latency under chunk-0 compute;
//  2) a0/a1 merged into one float2 LDS read (halves scalar ds_read count).
// Everything else is the exact round-16 kernel.
// ---------------------------------------------------------------------------

typedef unsigned short bf16_t;
typedef unsigned int u32x4 __attribute__((ext_vector_type(4)));
typedef _Float16 half8 __attribute__((ext_vector_type(8)));
typedef float f32x4 __attribute__((ext_vector_type(4)));

#define NSHARD 256
#define CHUNK 4096
#define UPD_NPB 8    // nodes per 256-thread block in update kernels

__device__ __forceinline__ float bf2f(bf16_t u) {
    return __uint_as_float(((unsigned int)u) << 16);
}
__device__ __forceinline__ bf16_t f2bf(float f) {
    unsigned int u = __float_as_uint(f);
    unsigned int r = (u + 0x7FFFu + ((u >> 16) & 1u)) >> 16;  // RNE
    return (bf16_t)r;
}

__device__ __forceinline__ unsigned int pack_half2(float a, float b) {
    _Float16 ha = (_Float16)a;
    _Float16 hb = (_Float16)b;
    unsigned short ua = __builtin_bit_cast(unsigned short, ha);
    unsigned short ub = __builtin_bit_cast(unsigned short, hb);
    return (unsigned int)ua | ((unsigned int)ub << 16);
}
__device__ __forceinline__ float2 unpack_half2(unsigned int u) {
    _Float16 lo = __builtin_bit_cast(_Float16, (unsigned short)(u & 0xFFFFu));
    _Float16 hi = __builtin_bit_cast(_Float16, (unsigned short)(u >> 16));
    return make_float2((float)lo, (float)hi);
}

__device__ __forceinline__ float gelu_tanh(float x) {
    float x3 = x * x * x;
    float t = tanhf(0.7978845608028654f * (x + 0.044715f * x3));
    return 0.5f * x * (1.0f + t);
}

// ---- edge dtype detection ------------------------------------------------
__global__ void k_detect(const int* __restrict__ ei, int* __restrict__ flag) {
    if (blockIdx.x == 0 && threadIdx.x == 0) {
        int is64 = 1;
        for (int i = 1; i < 256; i += 2)
            if (ei[i] != 0) { is64 = 0; break; }
        *flag = is64;
    }
}

// ---- CSR build v3 --------------------------------------------------------
__global__ __launch_bounds__(256) void k_count(const int* __restrict__ ei,
                        const int* __restrict__ flag, int* __restrict__ shard_cnt,
                        int e, int sn) {
    __shared__ int lc[NSHARD];
    if (threadIdx.x < NSHARD) lc[threadIdx.x] = 0;
    __syncthreads();
    int is64 = *flag;
    int beg = blockIdx.x * CHUNK;
    int end = min(beg + CHUNK, e);
    for (int i = beg + threadIdx.x; i < end; i += 256) {
        int d = is64 ? ei[2 * (e + i)] : ei[e + i];
        atomicAdd(&lc[d / sn], 1);
    }
    __syncthreads();
    if (threadIdx.x < NSHARD) {
        int c = lc[threadIdx.x];
        if (c) atomicAdd(&shard_cnt[threadIdx.x], c);
    }
}

__global__ void k_scan_shard(const int* __restrict__ shard_cnt,
                             int* __restrict__ shard_base, int* __restrict__ bcur) {
    __shared__ int s[NSHARD];
    int t = threadIdx.x;
    s[t] = shard_cnt[t];
    __syncthreads();
#pragma unroll
    for (int off = 1; off < NSHARD; off <<= 1) {
        int add = (t >= off) ? s[t - off] : 0;
        __syncthreads();
        s[t] += add;
        __syncthreads();
    }
    int excl = (t == 0) ? 0 : s[t - 1];
    shard_base[t] = excl;
    bcur[t] = excl;
    if (t == NSHARD - 1) shard_base[NSHARD] = s[t];
}

__global__ __launch_bounds__(256) void k_partition(const int* __restrict__ ei,
                        const int* __restrict__ flag, int* __restrict__ bcur,
                        int2* __restrict__ ebuf, int e, int sn) {
    __shared__ int lcnt[NSHARD];
    __shared__ int lbase[NSHARD];
    int is64 = *flag;
    int beg = blockIdx.x * CHUNK;
    int end = min(beg + CHUNK, e);
    if (threadIdx.x < NSHARD) lcnt[threadIdx.x] = 0;
    __syncthreads();
    for (int i = beg + threadIdx.x; i < end; i += 256) {
        int d = is64 ? ei[2 * (e + i)] : ei[e + i];
        atomicAdd(&lcnt[d / sn], 1);
    }
    __syncthreads();
    if (threadIdx.x < NSHARD) {
        int c = lcnt[threadIdx.x];
        lbase[threadIdx.x] = (c > 0) ? atomicAdd(&bcur[threadIdx.x], c) : 0;
        lcnt[threadIdx.x] = 0;
    }
    __syncthreads();
    for (int i = beg + threadIdx.x; i < end; i += 256) {
        int d = is64 ? ei[2 * (e + i)] : ei[e + i];
        int s = is64 ? ei[2 * i] : ei[i];
        int sh = d / sn;
        int pos = lbase[sh] + atomicAdd(&lcnt[sh], 1);
        ebuf[pos] = make_int2(s, d);
    }
}

__global__ __launch_bounds__(256) void k_distribute(const int* __restrict__ shard_base,
                        const int2* __restrict__ ebuf, int* __restrict__ csr_src,
                        int* __restrict__ row_ptr, int sn, int n) {
    __shared__ int lcnt[512];   // sn <= 512
    __shared__ int lcur[512];
    __shared__ int stmp[256];
    int sh = blockIdx.x;
    int node0 = sh * sn;
    if (node0 >= n) return;
    int nloc = min(sn, n - node0);
    int base = shard_base[sh];
    int bend = shard_base[sh + 1];
    for (int j = threadIdx.x; j < nloc; j += 256) lcnt[j] = 0;
    __syncthreads();
    for (int p = base + threadIdx.x; p < bend; p += 256) {
        int2 ed = ebuf[p];
        atomicAdd(&lcnt[ed.y - node0], 1);
    }
    __syncthreads();
    int carry = 0;
    for (int seg = 0; seg < nloc; seg += 256) {
        int idx = seg + threadIdx.x;
        int v = (idx < nloc) ? lcnt[idx] : 0;
        stmp[threadIdx.x] = v;
        __syncthreads();
#pragma unroll
        for (int off = 1; off < 256; off <<= 1) {
            int add = (threadIdx.x >= off) ? stmp[threadIdx.x - off] : 0;
            __syncthreads();
            stmp[threadIdx.x] += add;
            __syncthreads();
        }
        int incl = stmp[threadIdx.x];
        if (idx < nloc) {
            lcur[idx] = base + carry + incl - v;          // exclusive cursor
            row_ptr[node0 + idx + 1] = base + carry + incl;
        }
        carry += stmp[255];
        __syncthreads();
    }
    if (sh == 0 && threadIdx.x == 0) row_ptr[0] = 0;
    __syncthreads();
    for (int p = base + threadIdx.x; p < bend; p += 256) {
        int2 ed = ebuf[p];
        int pos = atomicAdd(&lcur[ed.y - node0], 1);
        csr_src[pos] = ed.x;
    }
}

// ---- fused embedding: h = x@W_in+b ; m16 = fp16(gelu(h@emb1_W+emb1_b)) ----
// Chunked-K x staging with register prefetch: chunk c+1 global loads issue
// before the compute barrier of chunk c. Accumulation order unchanged
// (k ascending, single accumulator per output) -> bit-identical.
__global__ __launch_bounds__(256) void k_embed_hm(const float* __restrict__ x,
                          const float* __restrict__ W_in, const float* __restrict__ b_in,
                          const float* __restrict__ W2, const float* __restrict__ b2,
                          float* __restrict__ h,
                          unsigned int* __restrict__ m16, int n) {
    __shared__ float sW[128 * 32];
    __shared__ float sX[64 * 68];
    __shared__ float sb1[32];
    __shared__ float sb2[64];
    int tid = threadIdx.x;
    for (int i = tid; i < 128 * 32; i += 256) sW[i] = W_in[i];
    for (int i = tid; i < 32; i += 256) sb1[i] = b_in[i];
    for (int i = tid; i < 64; i += 256) sb2[i] = b2[i];

    int node0 = blockIdx.x * 64;
    int tx = tid & 7;
    int ty = tid >> 3;
    float acc[2][4];
#pragma unroll
    for (int i = 0; i < 2; i++)
#pragma unroll
        for (int j = 0; j < 4; j++) acc[i][j] = 0.0f;

    int r = tid >> 2;
    int q0 = tid & 3;
    int node_r = node0 + r;
    bool okr = node_r < n;
    const float4* xrow = (const float4*)(x + (size_t)node_r * 128);

    // prefetch chunk 0 into registers
    float4 xb[4];
#pragma unroll
    for (int qq = 0; qq < 4; qq++) {
        int q = qq * 4 + q0;
        xb[qq] = okr ? xrow[q] : make_float4(0.f, 0.f, 0.f, 0.f);
    }

#pragma unroll
    for (int c = 0; c < 2; c++) {
        __syncthreads();   // c=0: sW/sb staged; c=1: chunk-0 reads done
#pragma unroll
        for (int qq = 0; qq < 4; qq++) {
            int ql = qq * 4 + q0;              // local float4 index 0..15
            float4 v = xb[qq];
            sX[(ql * 4 + 0) * 68 + r] = v.x;
            sX[(ql * 4 + 1) * 68 + r] = v.y;
            sX[(ql * 4 + 2) * 68 + r] = v.z;
            sX[(ql * 4 + 3) * 68 + r] = v.w;
        }
        if (c == 0) {
            // issue chunk-1 loads now: latency hides under chunk-0 compute
#pragma unroll
            for (int qq = 0; qq < 4; qq++) {
                int q = 16 + qq * 4 + q0;
                xb[qq] = okr ? xrow[q] : make_float4(0.f, 0.f, 0.f, 0.f);
            }
        }
        __syncthreads();
#pragma unroll 4
        for (int kl = 0; kl < 64; kl++) {
            int k = c * 64 + kl;
            float2 av = *(const float2*)&sX[kl * 68 + ty * 2];
            float a0 = av.x;
            float a1 = av.y;
            float4 wv = *(const float4*)&sW[k * 32 + tx * 4];
#pragma unroll
            for (int j = 0; j < 4; j++) {
                float w = (&wv.x)[j];
                acc[0][j] += a0 * w;
                acc[1][j] += a1 * w;
            }
        }
    }
    __syncthreads();

    float hv[2][4];
#pragma unroll
    for (int i = 0; i < 2; i++) {
        int node = node0 + ty * 2 + i;
#pragma unroll
        for (int j = 0; j < 4; j++) {
            hv[i][j] = acc[i][j] + sb1[tx * 4 + j];
            sX[(tx * 4 + j) * 68 + (ty * 2 + i)] = hv[i][j];
        }
        if (node < n) {
            float4 o = make_float4(hv[i][0], hv[i][1], hv[i][2], hv[i][3]);
            *(float4*)&h[(size_t)node * 32 + tx * 4] = o;
        }
    }
    for (int i = tid; i < 32 * 64; i += 256) sW[i] = W2[i];
    __syncthreads();

    int tx2 = tid & 15;
    int ty2 = tid >> 4;
    float acc2[4][4];
#pragma unroll
    for (int i = 0; i < 4; i++)
#pragma unroll
        for (int j = 0; j < 4; j++) acc2[i][j] = 0.0f;

#pragma unroll 4
    for (int k = 0; k < 32; k++) {
        float4 av = *(const float4*)&sX[k * 68 + ty2 * 4];
        float4 wv = *(const float4*)&sW[k * 64 + tx2 * 4];
        float a_[4] = {av.x, av.y, av.z, av.w};
#pragma unroll
        for (int i = 0; i < 4; i++)
#pragma unroll
            for (int j = 0; j < 4; j++)
                acc2[i][j] += a_[i] * (&wv.x)[j];
    }
#pragma unroll
    for (int i = 0; i < 4; i++) {
        int node = node0 + ty2 * 4 + i;
        if (node >= n) continue;
        float o0 = gelu_tanh(acc2[i][0] + sb2[tx2 * 4]);
        float o1 = gelu_tanh(acc2[i][1] + sb2[tx2 * 4 + 1]);
        float o2 = gelu_tanh(acc2[i][2] + sb2[tx2 * 4 + 2]);
        float o3 = gelu_tanh(acc2[i][3] + sb2[tx2 * 4 + 3]);
        *(uint2*)&m16[(size_t)node * 32 + tx2 * 2] =
            make_uint2(pack_half2(o0, o1), pack_half2(o2, o3));
    }
}

// agg16[node] = fp16 of sum over in-edges of m16[src].
__global__ void k_gather64h(const int* __restrict__ row_ptr, const int* __restrict__ csr_src,
                            const uint2* __restrict__ m16v,
                            unsigned int* __restrict__ agg16, int n) {
    int wave = (blockIdx.x * blockDim.x + threadIdx.x) >> 6;
    int lane = threadIdx.x & 63;
    int f = lane & 15;          // uint2 index in row (channels 4f .. 4f+3)
    int q = lane >> 4;          // quarter handles edges p == q (mod 4)
    if (wave >= n) return;
    int beg = row_ptr[wave], end = row_ptr[wave + 1];
    float a0 = 0.f, a1 = 0.f, a2 = 0.f, a3 = 0.f;
    int p = beg + q;
    for (; p + 4 < end; p += 8) {
        int s0 = csr_src[p], s1 = csr_src[p + 4];
        uint2 u = m16v[(size_t)s0 * 16 + f];
        uint2 v = m16v[(size_t)s1 * 16 + f];
        float2 ux = unpack_half2(u.x), uy = unpack_half2(u.y);
        float2 vx = unpack_half2(v.x), vy = unpack_half2(v.y);
        a0 += ux.x + vx.x; a1 += ux.y + vx.y;
        a2 += uy.x + vy.x; a3 += uy.y + vy.y;
    }
    if (p < end) {
        uint2 u = m16v[(size_t)csr_src[p] * 16 + f];
        float2 ux = unpack_half2(u.x), uy = unpack_half2(u.y);
        a0 += ux.x; a1 += ux.y; a2 += uy.x; a3 += uy.y;
    }
    a0 += __shfl_xor(a0, 16, 64); a0 += __shfl_xor(a0, 32, 64);
    a1 += __shfl_xor(a1, 16, 64); a1 += __shfl_xor(a1, 32, 64);
    a2 += __shfl_xor(a2, 16, 64); a2 += __shfl_xor(a2, 32, 64);
    a3 += __shfl_xor(a3, 16, 64); a3 += __shfl_xor(a3, 32, 64);
    if (q == 0)
        *(uint2*)&agg16[(size_t)wave * 32 + 2 * f] =
            make_uint2(pack_half2(a0, a1), pack_half2(a2, a3));
}

// ---------------------------------------------------------------------------
// B-fragment prep: pack [Ws;Wn] (K=128, 64 cols) as f16 hi/lo MFMA fragments.
// ---------------------------------------------------------------------------
__global__ __launch_bounds__(256) void k_prep_bfrag(
        const float* __restrict__ Ws1, const float* __restrict__ Wn1,
        const float* __restrict__ Ws2, const float* __restrict__ Wn2,
        u32x4* __restrict__ bfrag) {
    int tid = threadIdx.x;
    for (int it = 0; it < 16; it++) {
        int idx = it * 256 + tid;           // 0..4095
        int layer = idx >> 11;
        int hiLo  = (idx >> 10) & 1;
        int kb    = (idx >> 8) & 3;
        int ct    = (idx >> 6) & 3;
        int lane  = idx & 63;
        int col   = ct * 16 + (lane & 15);
        int kbase = kb * 32 + (lane >> 4) * 8;
        const float* Ws = layer ? Ws2 : Ws1;
        const float* Wn = layer ? Wn2 : Wn1;
        unsigned int hw[4];
#pragma unroll
        for (int jp = 0; jp < 4; jp++) {
            unsigned short hs[2];
#pragma unroll
            for (int t2 = 0; t2 < 2; t2++) {
                int k = kbase + jp * 2 + t2;
                float wv = (k < 64) ? Ws[k * 64 + col] : Wn[(k - 64) * 64 + col];
                _Float16 hi = (_Float16)wv;
                _Float16 ov = hiLo ? (_Float16)((wv - (float)hi) * 2048.0f) : hi;
                hs[t2] = __builtin_bit_cast(unsigned short, ov);
            }
            hw[jp] = (unsigned int)hs[0] | ((unsigned int)hs[1] << 16);
        }
        u32x4 v;
        v[0] = hw[0]; v[1] = hw[1]; v[2] = hw[2]; v[3] = hw[3];
        bfrag[idx] = v;
    }
}

// ---------------------------------------------------------------------------
// k_gnn v7 (MFMA): out = gelu([m16|agg16] @ [Ws;Wn]) via mfma_f32_16x16x32_f16
// with hi/lo-split B. 64 nodes/block (4 waves x 16 nodes x 64 cols).
// gnn1: m16out (in-place). gnn2 (m16out==null): theta/params/rotate.
// ---------------------------------------------------------------------------
__global__ __launch_bounds__(256) void k_gnn_mfma(
        const unsigned int* A0, const unsigned int* __restrict__ A1,
        const u32x4* __restrict__ bfrag, int layer,
        unsigned int* m16out,
        const float* w2, const float* b2, const int* __restrict__ row_ptr,
        const float* __restrict__ xs, float4* __restrict__ params,
        bf16_t* __restrict__ ysh, int n) {
    __shared__ float sTh[64];
    int tid = threadIdx.x;
    int w = tid >> 6, lane = tid & 63;
    int g = lane >> 4, c15 = lane & 15;
    int nodeBase = blockIdx.x * 64 + w * 16;

    // A fragments: row = nodeBase + c15 (clamped), k-span = kb*32 + g*8 .. +7
    int arow = nodeBase + c15;
    if (arow >= n) arow = n - 1;
    const u32x4* am = (const u32x4*)(A0 + (size_t)arow * 32);
    const u32x4* aa = (const u32x4*)(A1 + (size_t)arow * 32);
    u32x4 afr[4];
    afr[0] = am[g];
    afr[1] = am[4 + g];
    afr[2] = aa[g];
    afr[3] = aa[4 + g];

    const u32x4* bf = bfrag + layer * 2048;
    float o[4][4];
#pragma unroll
    for (int ct = 0; ct < 4; ct++) {
        f32x4 ah = {0.f, 0.f, 0.f, 0.f};
        f32x4 al = {0.f, 0.f, 0.f, 0.f};
#pragma unroll
        for (int kb = 0; kb < 4; kb++) {
            half8 a  = __builtin_bit_cast(half8, afr[kb]);
            half8 bh = __builtin_bit_cast(half8, bf[(kb << 8) + (ct << 6) + lane]);
            half8 bl = __builtin_bit_cast(half8, bf[1024 + (kb << 8) + (ct << 6) + lane]);
            ah = __builtin_amdgcn_mfma_f32_16x16x32_f16(a, bh, ah, 0, 0, 0);
            al = __builtin_amdgcn_mfma_f32_16x16x32_f16(a, bl, al, 0, 0, 0);
        }
#pragma unroll
        for (int r = 0; r < 4; r++)
            o[ct][r] = gelu_tanh(ah[r] + al[r] * (1.0f / 2048.0f));
    }

    if (m16out) {
        // D layout: row = g*4 + r, col = ct*16 + c15
        unsigned short* mo = (unsigned short*)m16out;
#pragma unroll
        for (int r = 0; r < 4; r++) {
            int node = nodeBase + g * 4 + r;
            if (node >= n) continue;
#pragma unroll
            for (int ct = 0; ct < 4; ct++) {
                _Float16 hv = (_Float16)o[ct][r];
                mo[(size_t)node * 64 + ct * 16 + c15] =
                    __builtin_bit_cast(unsigned short, hv);
            }
        }
        return;
    }

    // gnn2: theta dot over cols, then params + first rotate
    {
        float w2v[4];
#pragma unroll
        for (int ct = 0; ct < 4; ct++) w2v[ct] = w2[ct * 16 + c15];
        float part[4];
#pragma unroll
        for (int r = 0; r < 4; r++)
            part[r] = o[0][r] * w2v[0] + o[1][r] * w2v[1] +
                      o[2][r] * w2v[2] + o[3][r] * w2v[3];
#pragma unroll
        for (int d = 1; d < 16; d <<= 1)
#pragma unroll
            for (int r = 0; r < 4; r++) part[r] += __shfl_xor(part[r], d, 64);
        if (c15 == 0) {
#pragma unroll
            for (int r = 0; r < 4; r++) sTh[w * 16 + g * 4 + r] = part[r];
        }
    }
    __syncthreads();
    if (tid < 64) {
        int node = blockIdx.x * 64 + tid;
        if (node < n) {
            float theta = tanhf(sTh[tid] + b2[0]);
            float ang = 6.283185307179586f * theta;
            float cv = cosf(ang), sv = sinf(ang);
            float deg = (float)(row_ptr[node + 1] - row_ptr[node]);
            float rd = rsqrtf(deg + 1.0f);
            params[node] = make_float4(cv, sv, rd, 0.0f);
            const float4* xr = (const float4*)(xs + (size_t)node * 32);
            ushort4* yr = (ushort4*)(ysh + (size_t)node * 32);
#pragma unroll
            for (int q = 0; q < 4; q++) {
                float4 x0 = xr[q];
                float4 x1 = xr[q + 4];
                float x0_[4] = {x0.x, x0.y, x0.z, x0.w};
                float x1_[4] = {x1.x, x1.y, x1.z, x1.w};
                float y0[4], y1[4];
#pragma unroll
                for (int t2 = 0; t2 < 4; t2++) {
                    y0[t2] = rd * (cv * x0_[t2] - sv * x1_[t2]);
                    y1[t2] = rd * (sv * x0_[t2] + cv * x1_[t2]);
                }
                yr[q]     = make_ushort4(f2bf(y0[0]), f2bf(y0[1]), f2bf(y0[2]), f2bf(y0[3]));
                yr[q + 4] = make_ushort4(f2bf(y1[0]), f2bf(y1[1]), f2bf(y1[2]), f2bf(y1[3]));
            }
        }
    }
}

// S[node] = sum over in-edges of ysh[src] (bf16 rows = 64B).
__global__ void k_gather32(const int* __restrict__ row_ptr, const int* __restrict__ csr_src,
                           const uint2* __restrict__ yshv, float* __restrict__ S, int n) {
    int wave = (blockIdx.x * blockDim.x + threadIdx.x) >> 6;
    int lane = threadIdx.x & 63;
    int f = lane & 7;           // uint2 index: bf16 channels 4f .. 4f+3
    int o = lane >> 3;          // octet: handles edges p == o (mod 8)
    if (wave >= n) return;
    int beg = row_ptr[wave], end = row_ptr[wave + 1];
    float a0 = 0.f, a1 = 0.f, a2 = 0.f, a3 = 0.f;
    int p = beg + o;
    for (; p + 8 < end; p += 16) {
        int s0 = csr_src[p], s1 = csr_src[p + 8];
        uint2 u = yshv[(size_t)s0 * 8 + f];
        uint2 v = yshv[(size_t)s1 * 8 + f];
        a0 += __uint_as_float(u.x << 16) + __uint_as_float(v.x << 16);
        a1 += __uint_as_float(u.x & 0xFFFF0000u) + __uint_as_float(v.x & 0xFFFF0000u);
        a2 += __uint_as_float(u.y << 16) + __uint_as_float(v.y << 16);
        a3 += __uint_as_float(u.y & 0xFFFF0000u) + __uint_as_float(v.y & 0xFFFF0000u);
    }
    if (p < end) {
        uint2 u = yshv[(size_t)csr_src[p] * 8 + f];
        a0 += __uint_as_float(u.x << 16);
        a1 += __uint_as_float(u.x & 0xFFFF0000u);
        a2 += __uint_as_float(u.y << 16);
        a3 += __uint_as_float(u.y & 0xFFFF0000u);
    }
    a0 += __shfl_xor(a0, 8, 64); a0 += __shfl_xor(a0, 16, 64); a0 += __shfl_xor(a0, 32, 64);
    a1 += __shfl_xor(a1, 8, 64); a1 += __shfl_xor(a1, 16, 64); a1 += __shfl_xor(a1, 32, 64);
    a2 += __shfl_xor(a2, 8, 64); a2 += __shfl_xor(a2, 16, 64); a2 += __shfl_xor(a2, 32, 64);
    a3 += __shfl_xor(a3, 8, 64); a3 += __shfl_xor(a3, 16, 64); a3 += __shfl_xor(a3, 32, 64);
    if (o == 0)
        *(float4*)&S[(size_t)wave * 32 + 4 * f] = make_float4(a0, a1, a2, a3);
}

// ---------------------------------------------------------------------------
// Cooperative update kernels: 32 lanes per node, 8 nodes per 256-thread block.
// ---------------------------------------------------------------------------

__global__ __launch_bounds__(256) void k_update_mid(
                             float* __restrict__ xs, const float* __restrict__ S,
                             const float4* __restrict__ params, const float* __restrict__ Wd,
                             bf16_t* __restrict__ ysh, int n) {
    __shared__ float sWd[256];
    __shared__ __align__(16) float sLx[UPD_NPB][36];
    int tid = threadIdx.x;
    sWd[tid] = Wd[tid];
    int nl = tid >> 5;
    int c  = tid & 31;
    int h  = c & 15;
    int node = blockIdx.x * UPD_NPB + nl;
    bool ok = node < n;
    float4 pd = ok ? params[node] : make_float4(0.f, 0.f, 0.f, 0.f);
    float cd = pd.x, sd = pd.y, rd = pd.z;
    float sv = ok ? S[(size_t)node * 32 + c] : 0.0f;
    float xv = ok ? xs[(size_t)node * 32 + c] : 0.0f;
    float sp = __shfl_xor(sv, 16);
    float sgnA = (c < 16) ? sd : -sd;
    float a = rd * (cd * sv + sgnA * sp);
    sLx[nl][c] = xv - a;
    __syncthreads();
    float wc[16];
#pragma unroll
    for (int k = 0; k < 16; k++) wc[k] = sWd[k * 16 + h];
    const float* lrow = &sLx[nl][c & 16];
    float4 l0 = *(const float4*)(lrow);
    float4 l1 = *(const float4*)(lrow + 4);
    float4 l2 = *(const float4*)(lrow + 8);
    float4 l3 = *(const float4*)(lrow + 12);
    float lv[16] = {l0.x, l0.y, l0.z, l0.w, l1.x, l1.y, l1.z, l1.w,
                    l2.x, l2.y, l2.z, l2.w, l3.x, l3.y, l3.z, l3.w};
    float acc = 0.0f;
#pragma unroll
    for (int k = 0; k < 16; k++) acc += lv[k] * wc[k];
    float nx = xv - gelu_tanh(acc);
    float np = __shfl_xor(nx, 16);
    float sgnY = (c < 16) ? -sd : sd;
    float y = rd * (cd * nx + sgnY * np);
    if (ok) {
        xs[(size_t)node * 32 + c] = nx;
        ysh[(size_t)node * 32 + c] = f2bf(y);
    }
}

__global__ __launch_bounds__(256) void k_update_out(
                             const float* __restrict__ xs, const float* __restrict__ S,
                             const float4* __restrict__ params, const float* __restrict__ Wd,
                             const float* __restrict__ Wo, const float* __restrict__ bo,
                             float* __restrict__ out, int n) {
    __shared__ float sWd[256];
    __shared__ float sWo[320];
    __shared__ float sbo[16];
    __shared__ __align__(16) float sLx[UPD_NPB][36];
    __shared__ float sNx[UPD_NPB][36];
    int tid = threadIdx.x;
    sWd[tid] = Wd[tid];
    for (int i = tid; i < 320; i += 256) sWo[i] = Wo[i];
    if (tid < 10) sbo[tid] = bo[tid];
    int nl = tid >> 5;
    int c  = tid & 31;
    int h  = c & 15;
    int node = blockIdx.x * UPD_NPB + nl;
    bool ok = node < n;
    float4 pd = ok ? params[node] : make_float4(0.f, 0.f, 0.f, 0.f);
    float cd = pd.x, sd = pd.y, rd = pd.z;
    float sv = ok ? S[(size_t)node * 32 + c] : 0.0f;
    float xv = ok ? xs[(size_t)node * 32 + c] : 0.0f;
    float sp = __shfl_xor(sv, 16);
    float sgnA = (c < 16) ? sd : -sd;
    float a = rd * (cd * sv + sgnA * sp);
    sLx[nl][c] = xv - a;
    __syncthreads();
    float wc[16];
#pragma unroll
    for (int k = 0; k < 16; k++) wc[k] = sWd[k * 16 + h];
    const float* lrow = &sLx[nl][c & 16];
    float4 l0 = *(const float4*)(lrow);
    float4 l1 = *(const float4*)(lrow + 4);
    float4 l2 = *(const float4*)(lrow + 8);
    float4 l3 = *(const float4*)(lrow + 12);
    float lv[16] = {l0.x, l0.y, l0.z, l0.w, l1.x, l1.y, l1.z, l1.w,
                    l2.x, l2.y, l2.z, l2.w, l3.x, l3.y, l3.z, l3.w};
    float acc = 0.0f;
#pragma unroll
    for (int k = 0; k < 16; k++) acc += lv[k] * wc[k];
    float nx = xv - gelu_tanh(acc);
    sNx[nl][c] = nx;
    __syncthreads();
    if (tid < UPD_NPB * 10) {
        int nl2 = tid / 10;
        int j = tid - nl2 * 10;
        int node2 = blockIdx.x * UPD_NPB + nl2;
        if (node2 < n) {
            float acc2 = sbo[j];
#pragma unroll 8
            for (int k = 0; k < 32; k++) acc2 += sNx[nl2][k] * sWo[k * 10 + j];
            out[(size_t)node2 * 10 + j] = acc2;
        }
    }
}

static inline size_t align256(size_t x) { return (x + 255) & ~(size_t)255; }

extern "C" void kernel_launch(void* const* d_in, const int* in_sizes, int n_in,
                              void* d_out, int out_size, void* d_ws, size_t ws_size,
                              hipStream_t stream) {
    const float* x      = (const float*)d_in[0];
    const int*   ei     = (const int*)d_in[1];
    const float* W_in   = (const float*)d_in[2];
    const float* b_in   = (const float*)d_in[3];
    const float* emb1_W = (const float*)d_in[4];
    const float* emb1_b = (const float*)d_in[5];
    const float* Ws1    = (const float*)d_in[6];
    const float* Wn1    = (const float*)d_in[7];
    const float* Ws2    = (const float*)d_in[8];
    const float* Wn2    = (const float*)d_in[9];
    const float* emb2_W = (const float*)d_in[10];
    const float* emb2_b = (const float*)d_in[11];
    const float* W_diff = (const float*)d_in[12];
    const float* W_out  = (const float*)d_in[13];
    const float* b_out  = (const float*)d_in[14];

    int n = in_sizes[0] / 128;  // 100000
    int e = in_sizes[1] / 2;    // 1600000
    int sn = (n + NSHARD - 1) / NSHARD;   // nodes per shard (<=512 required)

    char* base = (char*)d_ws;
    size_t off = 0;
    int*    csr_src   = (int*)(base + off);    off = align256(off + (size_t)e * 4);
    int2*   ebuf      = (int2*)(base + off);   off = align256(off + (size_t)e * 8);
    int*    row_ptr   = (int*)(base + off);    off = align256(off + (size_t)(n + 1) * 4);
    int*    shard_cnt = (int*)(base + off);    off = align256(off + NSHARD * 4);
    int*    shard_base= (int*)(base + off);    off = align256(off + (NSHARD + 1) * 4);
    int*    bcur      = (int*)(base + off);    off = align256(off + NSHARD * 4);
    int*    flag      = (int*)(base + off);    off = align256(off + 16);
    float*  h         = (float*)(base + off);  off = align256(off + (size_t)n * 32 * 4);
    bf16_t* ysh       = (bf16_t*)(base + off); off = align256(off + (size_t)n * 32 * 2);
    float*  agg       = (float*)(base + off);  off = align256(off + (size_t)n * 64 * 4);
    float4* params    = (float4*)(base + off); off = align256(off + (size_t)n * 16);
    u32x4*  bfrag     = (u32x4*)(base + off);  off = align256(off + 4096 * 16);

    // fp16 shadow of m: aliases ebuf (dead after CSR build; sizes match).
    unsigned int* m16;
    if ((size_t)n * 64 * 2 + 4096 <= (size_t)e * 8) {
        m16 = (unsigned int*)ebuf;
    } else {
        m16 = (unsigned int*)(base + off);
        off = align256(off + (size_t)n * 64 * 2 + 4096);
    }
    unsigned int* agg16 = (unsigned int*)agg;   // packed fp16 view (gnn input)

    int tb64 = (n + 63) / 64;
    int pb = (e + CHUNK - 1) / CHUNK;
    int ub = (n + UPD_NPB - 1) / UPD_NPB;
    int gnnm = (n + 63) / 64;

    // CSR build v3: shard count -> shard scan -> partition -> distribute
    k_detect<<<1, 64, 0, stream>>>(ei, flag);
    hipMemsetAsync(shard_cnt, 0, NSHARD * 4, stream);
    k_count<<<pb, 256, 0, stream>>>(ei, flag, shard_cnt, e, sn);
    k_scan_shard<<<1, NSHARD, 0, stream>>>(shard_cnt, shard_base, bcur);
    k_partition<<<pb, 256, 0, stream>>>(ei, flag, bcur, ebuf, e, sn);
    k_distribute<<<NSHARD, 256, 0, stream>>>(shard_base, ebuf, csr_src, row_ptr, sn, n);

    // B-fragment prep (tiny; overlapped in-stream)
    k_prep_bfrag<<<1, 256, 0, stream>>>(Ws1, Wn1, Ws2, Wn2, bfrag);

    // fused embeddings (h fp32 + m16 fp16), pipelined chunked-K staging
    k_embed_hm<<<tb64, 256, 0, stream>>>(x, W_in, b_in, emb1_W, emb1_b, h, m16, n);

    // sheaf learner GNN layers (MFMA); gnn #2 fuses params + first rotate
    int gb64 = (n * 64 + 255) / 256;
    k_gather64h<<<gb64, 256, 0, stream>>>(row_ptr, csr_src, (const uint2*)m16, agg16, n);
    k_gnn_mfma<<<gnnm, 256, 0, stream>>>(m16, agg16, bfrag, 0, m16,
                                         nullptr, nullptr, nullptr, nullptr, nullptr, nullptr, n);
    k_gather64h<<<gb64, 256, 0, stream>>>(row_ptr, csr_src, (const uint2*)m16, agg16, n);
    k_gnn_mfma<<<gnnm, 256, 0, stream>>>(m16, agg16, bfrag, 1, nullptr,
                                         emb2_W, emb2_b, row_ptr, h, params, ysh, n);

    // diffusion: gather -> update(+rotate) -> gather -> update(+out)
    k_gather32<<<gb64, 256, 0, stream>>>(row_ptr, csr_src, (const uint2*)ysh, agg, n);
    k_update_mid<<<ub, 256, 0, stream>>>(h, agg, params, W_diff, ysh, n);
    k_gather32<<<gb64, 256, 0, stream>>>(row_ptr, csr_src, (const uint2*)ysh, agg, n);
    k_update_out<<<ub, 256, 0, stream>>>(h, agg, params, W_diff + 256,
                                         W_out, b_out, (float*)d_out, n);
}

// Round 19
// 422.016 us; speedup vs baseline: 1.0220x; 1.0220x over previous
//
#include <hip/hip_runtime.h>
#include <math.h>

// ---------------------------------------------------------------------------
// SheafDiffusion on MI355X — round 30: uint4 gather64h.
// Round-17 (431.3us): embed left the top-5 (<45us); k_gather64h is now top
// (44.9us x2; HBM 26%, VALU 38%, occ 67%) -- no longer latency-bound
// (33K rows in flight vs ~14K needed); bound by VMEM/VALU issue + random
// L2/L3 throughput. This round: widen gather64h lanes uint2->uint4
// (8 lanes/row, 8 octets, x2 unroll = 16 rows in flight): loop iterations,
// address math and csr_src loads halve; bytes unchanged. Reduction
// shfl_xor 8/16/32; coalesced uint4 store. (Regroups the edge sum mod-4 ->
// mod-8; same regrouping survived round 4 with absmax unchanged.)
// Everything else is the exact round-17 kernel.
// ---------------------------------------------------------------------------

typedef unsigned short bf16_t;
typedef unsigned int u32x4 __attribute__((ext_vector_type(4)));
typedef _Float16 half8 __attribute__((ext_vector_type(8)));
typedef float f32x4 __attribute__((ext_vector_type(4)));

#define NSHARD 256
#define CHUNK 4096
#define UPD_NPB 8    // nodes per 256-thread block in update kernels

__device__ __forceinline__ float bf2f(bf16_t u) {
    return __uint_as_float(((unsigned int)u) << 16);
}
__device__ __forceinline__ bf16_t f2bf(float f) {
    unsigned int u = __float_as_uint(f);
    unsigned int r = (u + 0x7FFFu + ((u >> 16) & 1u)) >> 16;  // RNE
    return (bf16_t)r;
}

__device__ __forceinline__ unsigned int pack_half2(float a, float b) {
    _Float16 ha = (_Float16)a;
    _Float16 hb = (_Float16)b;
    unsigned short ua = __builtin_bit_cast(unsigned short, ha);
    unsigned short ub = __builtin_bit_cast(unsigned short, hb);
    return (unsigned int)ua | ((unsigned int)ub << 16);
}
__device__ __forceinline__ float2 unpack_half2(unsigned int u) {
    _Float16 lo = __builtin_bit_cast(_Float16, (unsigned short)(u & 0xFFFFu));
    _Float16 hi = __builtin_bit_cast(_Float16, (unsigned short)(u >> 16));
    return make_float2((float)lo, (float)hi);
}

__device__ __forceinline__ float gelu_tanh(float x) {
    float x3 = x * x * x;
    float t = tanhf(0.7978845608028654f * (x + 0.044715f * x3));
    return 0.5f * x * (1.0f + t);
}

// ---- edge dtype detection ------------------------------------------------
__global__ void k_detect(const int* __restrict__ ei, int* __restrict__ flag) {
    if (blockIdx.x == 0 && threadIdx.x == 0) {
        int is64 = 1;
        for (int i = 1; i < 256; i += 2)
            if (ei[i] != 0) { is64 = 0; break; }
        *flag = is64;
    }
}

// ---- CSR build v3 --------------------------------------------------------
__global__ __launch_bounds__(256) void k_count(const int* __restrict__ ei,
                        const int* __restrict__ flag, int* __restrict__ shard_cnt,
                        int e, int sn) {
    __shared__ int lc[NSHARD];
    if (threadIdx.x < NSHARD) lc[threadIdx.x] = 0;
    __syncthreads();
    int is64 = *flag;
    int beg = blockIdx.x * CHUNK;
    int end = min(beg + CHUNK, e);
    for (int i = beg + threadIdx.x; i < end; i += 256) {
        int d = is64 ? ei[2 * (e + i)] : ei[e + i];
        atomicAdd(&lc[d / sn], 1);
    }
    __syncthreads();
    if (threadIdx.x < NSHARD) {
        int c = lc[threadIdx.x];
        if (c) atomicAdd(&shard_cnt[threadIdx.x], c);
    }
}

__global__ void k_scan_shard(const int* __restrict__ shard_cnt,
                             int* __restrict__ shard_base, int* __restrict__ bcur) {
    __shared__ int s[NSHARD];
    int t = threadIdx.x;
    s[t] = shard_cnt[t];
    __syncthreads();
#pragma unroll
    for (int off = 1; off < NSHARD; off <<= 1) {
        int add = (t >= off) ? s[t - off] : 0;
        __syncthreads();
        s[t] += add;
        __syncthreads();
    }
    int excl = (t == 0) ? 0 : s[t - 1];
    shard_base[t] = excl;
    bcur[t] = excl;
    if (t == NSHARD - 1) shard_base[NSHARD] = s[t];
}

__global__ __launch_bounds__(256) void k_partition(const int* __restrict__ ei,
                        const int* __restrict__ flag, int* __restrict__ bcur,
                        int2* __restrict__ ebuf, int e, int sn) {
    __shared__ int lcnt[NSHARD];
    __shared__ int lbase[NSHARD];
    int is64 = *flag;
    int beg = blockIdx.x * CHUNK;
    int end = min(beg + CHUNK, e);
    if (threadIdx.x < NSHARD) lcnt[threadIdx.x] = 0;
    __syncthreads();
    for (int i = beg + threadIdx.x; i < end; i += 256) {
        int d = is64 ? ei[2 * (e + i)] : ei[e + i];
        atomicAdd(&lcnt[d / sn], 1);
    }
    __syncthreads();
    if (threadIdx.x < NSHARD) {
        int c = lcnt[threadIdx.x];
        lbase[threadIdx.x] = (c > 0) ? atomicAdd(&bcur[threadIdx.x], c) : 0;
        lcnt[threadIdx.x] = 0;
    }
    __syncthreads();
    for (int i = beg + threadIdx.x; i < end; i += 256) {
        int d = is64 ? ei[2 * (e + i)] : ei[e + i];
        int s = is64 ? ei[2 * i] : ei[i];
        int sh = d / sn;
        int pos = lbase[sh] + atomicAdd(&lcnt[sh], 1);
        ebuf[pos] = make_int2(s, d);
    }
}

__global__ __launch_bounds__(256) void k_distribute(const int* __restrict__ shard_base,
                        const int2* __restrict__ ebuf, int* __restrict__ csr_src,
                        int* __restrict__ row_ptr, int sn, int n) {
    __shared__ int lcnt[512];   // sn <= 512
    __shared__ int lcur[512];
    __shared__ int stmp[256];
    int sh = blockIdx.x;
    int node0 = sh * sn;
    if (node0 >= n) return;
    int nloc = min(sn, n - node0);
    int base = shard_base[sh];
    int bend = shard_base[sh + 1];
    for (int j = threadIdx.x; j < nloc; j += 256) lcnt[j] = 0;
    __syncthreads();
    for (int p = base + threadIdx.x; p < bend; p += 256) {
        int2 ed = ebuf[p];
        atomicAdd(&lcnt[ed.y - node0], 1);
    }
    __syncthreads();
    int carry = 0;
    for (int seg = 0; seg < nloc; seg += 256) {
        int idx = seg + threadIdx.x;
        int v = (idx < nloc) ? lcnt[idx] : 0;
        stmp[threadIdx.x] = v;
        __syncthreads();
#pragma unroll
        for (int off = 1; off < 256; off <<= 1) {
            int add = (threadIdx.x >= off) ? stmp[threadIdx.x - off] : 0;
            __syncthreads();
            stmp[threadIdx.x] += add;
            __syncthreads();
        }
        int incl = stmp[threadIdx.x];
        if (idx < nloc) {
            lcur[idx] = base + carry + incl - v;          // exclusive cursor
            row_ptr[node0 + idx + 1] = base + carry + incl;
        }
        carry += stmp[255];
        __syncthreads();
    }
    if (sh == 0 && threadIdx.x == 0) row_ptr[0] = 0;
    __syncthreads();
    for (int p = base + threadIdx.x; p < bend; p += 256) {
        int2 ed = ebuf[p];
        int pos = atomicAdd(&lcur[ed.y - node0], 1);
        csr_src[pos] = ed.x;
    }
}

// ---- fused embedding: h = x@W_in+b ; m16 = fp16(gelu(h@emb1_W+emb1_b)) ----
// Chunked-K x staging with register prefetch (round-17, bit-identical chains).
__global__ __launch_bounds__(256) void k_embed_hm(const float* __restrict__ x,
                          const float* __restrict__ W_in, const float* __restrict__ b_in,
                          const float* __restrict__ W2, const float* __restrict__ b2,
                          float* __restrict__ h,
                          unsigned int* __restrict__ m16, int n) {
    __shared__ float sW[128 * 32];
    __shared__ float sX[64 * 68];
    __shared__ float sb1[32];
    __shared__ float sb2[64];
    int tid = threadIdx.x;
    for (int i = tid; i < 128 * 32; i += 256) sW[i] = W_in[i];
    for (int i = tid; i < 32; i += 256) sb1[i] = b_in[i];
    for (int i = tid; i < 64; i += 256) sb2[i] = b2[i];

    int node0 = blockIdx.x * 64;
    int tx = tid & 7;
    int ty = tid >> 3;
    float acc[2][4];
#pragma unroll
    for (int i = 0; i < 2; i++)
#pragma unroll
        for (int j = 0; j < 4; j++) acc[i][j] = 0.0f;

    int r = tid >> 2;
    int q0 = tid & 3;
    int node_r = node0 + r;
    bool okr = node_r < n;
    const float4* xrow = (const float4*)(x + (size_t)node_r * 128);

    // prefetch chunk 0 into registers
    float4 xb[4];
#pragma unroll
    for (int qq = 0; qq < 4; qq++) {
        int q = qq * 4 + q0;
        xb[qq] = okr ? xrow[q] : make_float4(0.f, 0.f, 0.f, 0.f);
    }

#pragma unroll
    for (int c = 0; c < 2; c++) {
        __syncthreads();   // c=0: sW/sb staged; c=1: chunk-0 reads done
#pragma unroll
        for (int qq = 0; qq < 4; qq++) {
            int ql = qq * 4 + q0;              // local float4 index 0..15
            float4 v = xb[qq];
            sX[(ql * 4 + 0) * 68 + r] = v.x;
            sX[(ql * 4 + 1) * 68 + r] = v.y;
            sX[(ql * 4 + 2) * 68 + r] = v.z;
            sX[(ql * 4 + 3) * 68 + r] = v.w;
        }
        if (c == 0) {
            // issue chunk-1 loads now: latency hides under chunk-0 compute
#pragma unroll
            for (int qq = 0; qq < 4; qq++) {
                int q = 16 + qq * 4 + q0;
                xb[qq] = okr ? xrow[q] : make_float4(0.f, 0.f, 0.f, 0.f);
            }
        }
        __syncthreads();
#pragma unroll 4
        for (int kl = 0; kl < 64; kl++) {
            int k = c * 64 + kl;
            float2 av = *(const float2*)&sX[kl * 68 + ty * 2];
            float a0 = av.x;
            float a1 = av.y;
            float4 wv = *(const float4*)&sW[k * 32 + tx * 4];
#pragma unroll
            for (int j = 0; j < 4; j++) {
                float w = (&wv.x)[j];
                acc[0][j] += a0 * w;
                acc[1][j] += a1 * w;
            }
        }
    }
    __syncthreads();

    float hv[2][4];
#pragma unroll
    for (int i = 0; i < 2; i++) {
        int node = node0 + ty * 2 + i;
#pragma unroll
        for (int j = 0; j < 4; j++) {
            hv[i][j] = acc[i][j] + sb1[tx * 4 + j];
            sX[(tx * 4 + j) * 68 + (ty * 2 + i)] = hv[i][j];
        }
        if (node < n) {
            float4 o = make_float4(hv[i][0], hv[i][1], hv[i][2], hv[i][3]);
            *(float4*)&h[(size_t)node * 32 + tx * 4] = o;
        }
    }
    for (int i = tid; i < 32 * 64; i += 256) sW[i] = W2[i];
    __syncthreads();

    int tx2 = tid & 15;
    int ty2 = tid >> 4;
    float acc2[4][4];
#pragma unroll
    for (int i = 0; i < 4; i++)
#pragma unroll
        for (int j = 0; j < 4; j++) acc2[i][j] = 0.0f;

#pragma unroll 4
    for (int k = 0; k < 32; k++) {
        float4 av = *(const float4*)&sX[k * 68 + ty2 * 4];
        float4 wv = *(const float4*)&sW[k * 64 + tx2 * 4];
        float a_[4] = {av.x, av.y, av.z, av.w};
#pragma unroll
        for (int i = 0; i < 4; i++)
#pragma unroll
            for (int j = 0; j < 4; j++)
                acc2[i][j] += a_[i] * (&wv.x)[j];
    }
#pragma unroll
    for (int i = 0; i < 4; i++) {
        int node = node0 + ty2 * 4 + i;
        if (node >= n) continue;
        float o0 = gelu_tanh(acc2[i][0] + sb2[tx2 * 4]);
        float o1 = gelu_tanh(acc2[i][1] + sb2[tx2 * 4 + 1]);
        float o2 = gelu_tanh(acc2[i][2] + sb2[tx2 * 4 + 2]);
        float o3 = gelu_tanh(acc2[i][3] + sb2[tx2 * 4 + 3]);
        *(uint2*)&m16[(size_t)node * 32 + tx2 * 2] =
            make_uint2(pack_half2(o0, o1), pack_half2(o2, o3));
    }
}

// agg16[node] = fp16 of sum over in-edges of m16[src].
// uint4 lanes: 8 lanes/row (16B each), 8 octets, x2 unroll = 16 rows in flight.
__global__ void k_gather64h(const int* __restrict__ row_ptr, const int* __restrict__ csr_src,
                            const u32x4* __restrict__ m16v,
                            unsigned int* __restrict__ agg16, int n) {
    int wave = (blockIdx.x * blockDim.x + threadIdx.x) >> 6;
    int lane = threadIdx.x & 63;
    int f = lane & 7;           // uint4 index in row (channels 8f .. 8f+7)
    int o = lane >> 3;          // octet handles edges p == o (mod 8)
    if (wave >= n) return;
    int beg = row_ptr[wave], end = row_ptr[wave + 1];
    float a[8] = {0.f, 0.f, 0.f, 0.f, 0.f, 0.f, 0.f, 0.f};
    int p = beg + o;
    for (; p + 8 < end; p += 16) {
        int s0 = csr_src[p], s1 = csr_src[p + 8];
        u32x4 u = m16v[(size_t)s0 * 8 + f];
        u32x4 v = m16v[(size_t)s1 * 8 + f];
#pragma unroll
        for (int j = 0; j < 4; j++) {
            float2 fu = unpack_half2(u[j]);
            float2 fv = unpack_half2(v[j]);
            a[2 * j]     += fu.x + fv.x;
            a[2 * j + 1] += fu.y + fv.y;
        }
    }
    if (p < end) {
        u32x4 u = m16v[(size_t)csr_src[p] * 8 + f];
#pragma unroll
        for (int j = 0; j < 4; j++) {
            float2 fu = unpack_half2(u[j]);
            a[2 * j]     += fu.x;
            a[2 * j + 1] += fu.y;
        }
    }
#pragma unroll
    for (int j = 0; j < 8; j++) {
        a[j] += __shfl_xor(a[j], 8, 64);
        a[j] += __shfl_xor(a[j], 16, 64);
        a[j] += __shfl_xor(a[j], 32, 64);
    }
    if (o == 0) {
        u32x4 w;
        w[0] = pack_half2(a[0], a[1]);
        w[1] = pack_half2(a[2], a[3]);
        w[2] = pack_half2(a[4], a[5]);
        w[3] = pack_half2(a[6], a[7]);
        *(u32x4*)&agg16[(size_t)wave * 32 + 4 * f] = w;
    }
}

// ---------------------------------------------------------------------------
// B-fragment prep: pack [Ws;Wn] (K=128, 64 cols) as f16 hi/lo MFMA fragments.
// ---------------------------------------------------------------------------
__global__ __launch_bounds__(256) void k_prep_bfrag(
        const float* __restrict__ Ws1, const float* __restrict__ Wn1,
        const float* __restrict__ Ws2, const float* __restrict__ Wn2,
        u32x4* __restrict__ bfrag) {
    int tid = threadIdx.x;
    for (int it = 0; it < 16; it++) {
        int idx = it * 256 + tid;           // 0..4095
        int layer = idx >> 11;
        int hiLo  = (idx >> 10) & 1;
        int kb    = (idx >> 8) & 3;
        int ct    = (idx >> 6) & 3;
        int lane  = idx & 63;
        int col   = ct * 16 + (lane & 15);
        int kbase = kb * 32 + (lane >> 4) * 8;
        const float* Ws = layer ? Ws2 : Ws1;
        const float* Wn = layer ? Wn2 : Wn1;
        unsigned int hw[4];
#pragma unroll
        for (int jp = 0; jp < 4; jp++) {
            unsigned short hs[2];
#pragma unroll
            for (int t2 = 0; t2 < 2; t2++) {
                int k = kbase + jp * 2 + t2;
                float wv = (k < 64) ? Ws[k * 64 + col] : Wn[(k - 64) * 64 + col];
                _Float16 hi = (_Float16)wv;
                _Float16 ov = hiLo ? (_Float16)((wv - (float)hi) * 2048.0f) : hi;
                hs[t2] = __builtin_bit_cast(unsigned short, ov);
            }
            hw[jp] = (unsigned int)hs[0] | ((unsigned int)hs[1] << 16);
        }
        u32x4 v;
        v[0] = hw[0]; v[1] = hw[1]; v[2] = hw[2]; v[3] = hw[3];
        bfrag[idx] = v;
    }
}

// ---------------------------------------------------------------------------
// k_gnn v7 (MFMA): out = gelu([m16|agg16] @ [Ws;Wn]) via mfma_f32_16x16x32_f16
// with hi/lo-split B. 64 nodes/block (4 waves x 16 nodes x 64 cols).
// gnn1: m16out (in-place). gnn2 (m16out==null): theta/params/rotate.
// ---------------------------------------------------------------------------
__global__ __launch_bounds__(256) void k_gnn_mfma(
        const unsigned int* A0, const unsigned int* __restrict__ A1,
        const u32x4* __restrict__ bfrag, int layer,
        unsigned int* m16out,
        const float* w2, const float* b2, const int* __restrict__ row_ptr,
        const float* __restrict__ xs, float4* __restrict__ params,
        bf16_t* __restrict__ ysh, int n) {
    __shared__ float sTh[64];
    int tid = threadIdx.x;
    int w = tid >> 6, lane = tid & 63;
    int g = lane >> 4, c15 = lane & 15;
    int nodeBase = blockIdx.x * 64 + w * 16;

    // A fragments: row = nodeBase + c15 (clamped), k-span = kb*32 + g*8 .. +7
    int arow = nodeBase + c15;
    if (arow >= n) arow = n - 1;
    const u32x4* am = (const u32x4*)(A0 + (size_t)arow * 32);
    const u32x4* aa = (const u32x4*)(A1 + (size_t)arow * 32);
    u32x4 afr[4];
    afr[0] = am[g];
    afr[1] = am[4 + g];
    afr[2] = aa[g];
    afr[3] = aa[4 + g];

    const u32x4* bf = bfrag + layer * 2048;
    float o[4][4];
#pragma unroll
    for (int ct = 0; ct < 4; ct++) {
        f32x4 ah = {0.f, 0.f, 0.f, 0.f};
        f32x4 al = {0.f, 0.f, 0.f, 0.f};
#pragma unroll
        for (int kb = 0; kb < 4; kb++) {
            half8 a  = __builtin_bit_cast(half8, afr[kb]);
            half8 bh = __builtin_bit_cast(half8, bf[(kb << 8) + (ct << 6) + lane]);
            half8 bl = __builtin_bit_cast(half8, bf[1024 + (kb << 8) + (ct << 6) + lane]);
            ah = __builtin_amdgcn_mfma_f32_16x16x32_f16(a, bh, ah, 0, 0, 0);
            al = __builtin_amdgcn_mfma_f32_16x16x32_f16(a, bl, al, 0, 0, 0);
        }
#pragma unroll
        for (int r = 0; r < 4; r++)
            o[ct][r] = gelu_tanh(ah[r] + al[r] * (1.0f / 2048.0f));
    }

    if (m16out) {
        // D layout: row = g*4 + r, col = ct*16 + c15
        unsigned short* mo = (unsigned short*)m16out;
#pragma unroll
        for (int r = 0; r < 4; r++) {
            int node = nodeBase + g * 4 + r;
            if (node >= n) continue;
#pragma unroll
            for (int ct = 0; ct < 4; ct++) {
                _Float16 hv = (_Float16)o[ct][r];
                mo[(size_t)node * 64 + ct * 16 + c15] =
                    __builtin_bit_cast(unsigned short, hv);
            }
        }
        return;
    }

    // gnn2: theta dot over cols, then params + first rotate
    {
        float w2v[4];
#pragma unroll
        for (int ct = 0; ct < 4; ct++) w2v[ct] = w2[ct * 16 + c15];
        float part[4];
#pragma unroll
        for (int r = 0; r < 4; r++)
            part[r] = o[0][r] * w2v[0] + o[1][r] * w2v[1] +
                      o[2][r] * w2v[2] + o[3][r] * w2v[3];
#pragma unroll
        for (int d = 1; d < 16; d <<= 1)
#pragma unroll
            for (int r = 0; r < 4; r++) part[r] += __shfl_xor(part[r], d, 64);
        if (c15 == 0) {
#pragma unroll
            for (int r = 0; r < 4; r++) sTh[w * 16 + g * 4 + r] = part[r];
        }
    }
    __syncthreads();
    if (tid < 64) {
        int node = blockIdx.x * 64 + tid;
        if (node < n) {
            float theta = tanhf(sTh[tid] + b2[0]);
            float ang = 6.283185307179586f * theta;
            float cv = cosf(ang), sv = sinf(ang);
            float deg = (float)(row_ptr[node + 1] - row_ptr[node]);
            float rd = rsqrtf(deg + 1.0f);
            params[node] = make_float4(cv, sv, rd, 0.0f);
            const float4* xr = (const float4*)(xs + (size_t)node * 32);
            ushort4* yr = (ushort4*)(ysh + (size_t)node * 32);
#pragma unroll
            for (int q = 0; q < 4; q++) {
                float4 x0 = xr[q];
                float4 x1 = xr[q + 4];
                float x0_[4] = {x0.x, x0.y, x0.z, x0.w};
                float x1_[4] = {x1.x, x1.y, x1.z, x1.w};
                float y0[4], y1[4];
#pragma unroll
                for (int t2 = 0; t2 < 4; t2++) {
                    y0[t2] = rd * (cv * x0_[t2] - sv * x1_[t2]);
                    y1[t2] = rd * (sv * x0_[t2] + cv * x1_[t2]);
                }
                yr[q]     = make_ushort4(f2bf(y0[0]), f2bf(y0[1]), f2bf(y0[2]), f2bf(y0[3]));
                yr[q + 4] = make_ushort4(f2bf(y1[0]), f2bf(y1[1]), f2bf(y1[2]), f2bf(y1[3]));
            }
        }
    }
}

// S[node] = sum over in-edges of ysh[src] (bf16 rows = 64B).
__global__ void k_gather32(const int* __restrict__ row_ptr, const int* __restrict__ csr_src,
                           const uint2* __restrict__ yshv, float* __restrict__ S, int n) {
    int wave = (blockIdx.x * blockDim.x + threadIdx.x) >> 6;
    int lane = threadIdx.x & 63;
    int f = lane & 7;           // uint2 index: bf16 channels 4f .. 4f+3
    int o = lane >> 3;          // octet: handles edges p == o (mod 8)
    if (wave >= n) return;
    int beg = row_ptr[wave], end = row_ptr[wave + 1];
    float a0 = 0.f, a1 = 0.f, a2 = 0.f, a3 = 0.f;
    int p = beg + o;
    for (; p + 8 < end; p += 16) {
        int s0 = csr_src[p], s1 = csr_src[p + 8];
        uint2 u = yshv[(size_t)s0 * 8 + f];
        uint2 v = yshv[(size_t)s1 * 8 + f];
        a0 += __uint_as_float(u.x << 16) + __uint_as_float(v.x << 16);
        a1 += __uint_as_float(u.x & 0xFFFF0000u) + __uint_as_float(v.x & 0xFFFF0000u);
        a2 += __uint_as_float(u.y << 16) + __uint_as_float(v.y << 16);
        a3 += __uint_as_float(u.y & 0xFFFF0000u) + __uint_as_float(v.y & 0xFFFF0000u);
    }
    if (p < end) {
        uint2 u = yshv[(size_t)csr_src[p] * 8 + f];
        a0 += __uint_as_float(u.x << 16);
        a1 += __uint_as_float(u.x & 0xFFFF0000u);
        a2 += __uint_as_float(u.y << 16);
        a3 += __uint_as_float(u.y & 0xFFFF0000u);
    }
    a0 += __shfl_xor(a0, 8, 64); a0 += __shfl_xor(a0, 16, 64); a0 += __shfl_xor(a0, 32, 64);
    a1 += __shfl_xor(a1, 8, 64); a1 += __shfl_xor(a1, 16, 64); a1 += __shfl_xor(a1, 32, 64);
    a2 += __shfl_xor(a2, 8, 64); a2 += __shfl_xor(a2, 16, 64); a2 += __shfl_xor(a2, 32, 64);
    a3 += __shfl_xor(a3, 8, 64); a3 += __shfl_xor(a3, 16, 64); a3 += __shfl_xor(a3, 32, 64);
    if (o == 0)
        *(float4*)&S[(size_t)wave * 32 + 4 * f] = make_float4(a0, a1, a2, a3);
}

// ---------------------------------------------------------------------------
// Cooperative update kernels: 32 lanes per node, 8 nodes per 256-thread block.
// ---------------------------------------------------------------------------

__global__ __launch_bounds__(256) void k_update_mid(
                             float* __restrict__ xs, const float* __restrict__ S,
                             const float4* __restrict__ params, const float* __restrict__ Wd,
                             bf16_t* __restrict__ ysh, int n) {
    __shared__ float sWd[256];
    __shared__ __align__(16) float sLx[UPD_NPB][36];
    int tid = threadIdx.x;
    sWd[tid] = Wd[tid];
    int nl = tid >> 5;
    int c  = tid & 31;
    int h  = c & 15;
    int node = blockIdx.x * UPD_NPB + nl;
    bool ok = node < n;
    float4 pd = ok ? params[node] : make_float4(0.f, 0.f, 0.f, 0.f);
    float cd = pd.x, sd = pd.y, rd = pd.z;
    float sv = ok ? S[(size_t)node * 32 + c] : 0.0f;
    float xv = ok ? xs[(size_t)node * 32 + c] : 0.0f;
    float sp = __shfl_xor(sv, 16);
    float sgnA = (c < 16) ? sd : -sd;
    float a = rd * (cd * sv + sgnA * sp);
    sLx[nl][c] = xv - a;
    __syncthreads();
    float wc[16];
#pragma unroll
    for (int k = 0; k < 16; k++) wc[k] = sWd[k * 16 + h];
    const float* lrow = &sLx[nl][c & 16];
    float4 l0 = *(const float4*)(lrow);
    float4 l1 = *(const float4*)(lrow + 4);
    float4 l2 = *(const float4*)(lrow + 8);
    float4 l3 = *(const float4*)(lrow + 12);
    float lv[16] = {l0.x, l0.y, l0.z, l0.w, l1.x, l1.y, l1.z, l1.w,
                    l2.x, l2.y, l2.z, l2.w, l3.x, l3.y, l3.z, l3.w};
    float acc = 0.0f;
#pragma unroll
    for (int k = 0; k < 16; k++) acc += lv[k] * wc[k];
    float nx = xv - gelu_tanh(acc);
    float np = __shfl_xor(nx, 16);
    float sgnY = (c < 16) ? -sd : sd;
    float y = rd * (cd * nx + sgnY * np);
    if (ok) {
        xs[(size_t)node * 32 + c] = nx;
        ysh[(size_t)node * 32 + c] = f2bf(y);
    }
}

__global__ __launch_bounds__(256) void k_update_out(
                             const float* __restrict__ xs, const float* __restrict__ S,
                             const float4* __restrict__ params, const float* __restrict__ Wd,
                             const float* __restrict__ Wo, const float* __restrict__ bo,
                             float* __restrict__ out, int n) {
    __shared__ float sWd[256];
    __shared__ float sWo[320];
    __shared__ float sbo[16];
    __shared__ __align__(16) float sLx[UPD_NPB][36];
    __shared__ float sNx[UPD_NPB][36];
    int tid = threadIdx.x;
    sWd[tid] = Wd[tid];
    for (int i = tid; i < 320; i += 256) sWo[i] = Wo[i];
    if (tid < 10) sbo[tid] = bo[tid];
    int nl = tid >> 5;
    int c  = tid & 31;
    int h  = c & 15;
    int node = blockIdx.x * UPD_NPB + nl;
    bool ok = node < n;
    float4 pd = ok ? params[node] : make_float4(0.f, 0.f, 0.f, 0.f);
    float cd = pd.x, sd = pd.y, rd = pd.z;
    float sv = ok ? S[(size_t)node * 32 + c] : 0.0f;
    float xv = ok ? xs[(size_t)node * 32 + c] : 0.0f;
    float sp = __shfl_xor(sv, 16);
    float sgnA = (c < 16) ? sd : -sd;
    float a = rd * (cd * sv + sgnA * sp);
    sLx[nl][c] = xv - a;
    __syncthreads();
    float wc[16];
#pragma unroll
    for (int k = 0; k < 16; k++) wc[k] = sWd[k * 16 + h];
    const float* lrow = &sLx[nl][c & 16];
    float4 l0 = *(const float4*)(lrow);
    float4 l1 = *(const float4*)(lrow + 4);
    float4 l2 = *(const float4*)(lrow + 8);
    float4 l3 = *(const float4*)(lrow + 12);
    float lv[16] = {l0.x, l0.y, l0.z, l0.w, l1.x, l1.y, l1.z, l1.w,
                    l2.x, l2.y, l2.z, l2.w, l3.x, l3.y, l3.z, l3.w};
    float acc = 0.0f;
#pragma unroll
    for (int k = 0; k < 16; k++) acc += lv[k] * wc[k];
    float nx = xv - gelu_tanh(acc);
    sNx[nl][c] = nx;
    __syncthreads();
    if (tid < UPD_NPB * 10) {
        int nl2 = tid / 10;
        int j = tid - nl2 * 10;
        int node2 = blockIdx.x * UPD_NPB + nl2;
        if (node2 < n) {
            float acc2 = sbo[j];
#pragma unroll 8
            for (int k = 0; k < 32; k++) acc2 += sNx[nl2][k] * sWo[k * 10 + j];
            out[(size_t)node2 * 10 + j] = acc2;
        }
    }
}

static inline size_t align256(size_t x) { return (x + 255) & ~(size_t)255; }

extern "C" void kernel_launch(void* const* d_in, const int* in_sizes, int n_in,
                              void* d_out, int out_size, void* d_ws, size_t ws_size,
                              hipStream_t stream) {
    const float* x      = (const float*)d_in[0];
    const int*   ei     = (const int*)d_in[1];
    const float* W_in   = (const float*)d_in[2];
    const float* b_in   = (const float*)d_in[3];
    const float* emb1_W = (const float*)d_in[4];
    const float* emb1_b = (const float*)d_in[5];
    const float* Ws1    = (const float*)d_in[6];
    const float* Wn1    = (const float*)d_in[7];
    const float* Ws2    = (const float*)d_in[8];
    const float* Wn2    = (const float*)d_in[9];
    const float* emb2_W = (const float*)d_in[10];
    const float* emb2_b = (const float*)d_in[11];
    const float* W_diff = (const float*)d_in[12];
    const float* W_out  = (const float*)d_in[13];
    const float* b_out  = (const float*)d_in[14];

    int n = in_sizes[0] / 128;  // 100000
    int e = in_sizes[1] / 2;    // 1600000
    int sn = (n + NSHARD - 1) / NSHARD;   // nodes per shard (<=512 required)

    char* base = (char*)d_ws;
    size_t off = 0;
    int*    csr_src   = (int*)(base + off);    off = align256(off + (size_t)e * 4);
    int2*   ebuf      = (int2*)(base + off);   off = align256(off + (size_t)e * 8);
    int*    row_ptr   = (int*)(base + off);    off = align256(off + (size_t)(n + 1) * 4);
    int*    shard_cnt = (int*)(base + off);    off = align256(off + NSHARD * 4);
    int*    shard_base= (int*)(base + off);    off = align256(off + (NSHARD + 1) * 4);
    int*    bcur      = (int*)(base + off);    off = align256(off + NSHARD * 4);
    int*    flag      = (int*)(base + off);    off = align256(off + 16);
    float*  h         = (float*)(base + off);  off = align256(off + (size_t)n * 32 * 4);
    bf16_t* ysh       = (bf16_t*)(base + off); off = align256(off + (size_t)n * 32 * 2);
    float*  agg       = (float*)(base + off);  off = align256(off + (size_t)n * 64 * 4);
    float4* params    = (float4*)(base + off); off = align256(off + (size_t)n * 16);
    u32x4*  bfrag     = (u32x4*)(base + off);  off = align256(off + 4096 * 16);

    // fp16 shadow of m: aliases ebuf (dead after CSR build; sizes match).
    unsigned int* m16;
    if ((size_t)n * 64 * 2 + 4096 <= (size_t)e * 8) {
        m16 = (unsigned int*)ebuf;
    } else {
        m16 = (unsigned int*)(base + off);
        off = align256(off + (size_t)n * 64 * 2 + 4096);
    }
    unsigned int* agg16 = (unsigned int*)agg;   // packed fp16 view (gnn input)

    int tb64 = (n + 63) / 64;
    int pb = (e + CHUNK - 1) / CHUNK;
    int ub = (n + UPD_NPB - 1) / UPD_NPB;
    int gnnm = (n + 63) / 64;

    // CSR build v3: shard count -> shard scan -> partition -> distribute
    k_detect<<<1, 64, 0, stream>>>(ei, flag);
    hipMemsetAsync(shard_cnt, 0, NSHARD * 4, stream);
    k_count<<<pb, 256, 0, stream>>>(ei, flag, shard_cnt, e, sn);
    k_scan_shard<<<1, NSHARD, 0, stream>>>(shard_cnt, shard_base, bcur);
    k_partition<<<pb, 256, 0, stream>>>(ei, flag, bcur, ebuf, e, sn);
    k_distribute<<<NSHARD, 256, 0, stream>>>(shard_base, ebuf, csr_src, row_ptr, sn, n);

    // B-fragment prep (tiny; overlapped in-stream)
    k_prep_bfrag<<<1, 256, 0, stream>>>(Ws1, Wn1, Ws2, Wn2, bfrag);

    // fused embeddings (h fp32 + m16 fp16), pipelined chunked-K staging
    k_embed_hm<<<tb64, 256, 0, stream>>>(x, W_in, b_in, emb1_W, emb1_b, h, m16, n);

    // sheaf learner GNN layers (MFMA); gnn #2 fuses params + first rotate
    int gb64 = (n * 64 + 255) / 256;
    k_gather64h<<<gb64, 256, 0, stream>>>(row_ptr, csr_src, (const u32x4*)m16, agg16, n);
    k_gnn_mfma<<<gnnm, 256, 0, stream>>>(m16, agg16, bfrag, 0, m16,
                                         nullptr, nullptr, nullptr, nullptr, nullptr, nullptr, n);
    k_gather64h<<<gb64, 256, 0, stream>>>(row_ptr, csr_src, (const u32x4*)m16, agg16, n);
    k_gnn_mfma<<<gnnm, 256, 0, stream>>>(m16, agg16, bfrag, 1, nullptr,
                                         emb2_W, emb2_b, row_ptr, h, params, ysh, n);

    // diffusion: gather -> update(+rotate) -> gather -> update(+out)
    k_gather32<<<gb64, 256, 0, stream>>>(row_ptr, csr_src, (const uint2*)ysh, agg, n);
    k_update_mid<<<ub, 256, 0, stream>>>(h, agg, params, W_diff, ysh, n);
    k_gather32<<<gb64, 256, 0, stream>>>(row_ptr, csr_src, (const uint2*)ysh, agg, n);
    k_update_out<<<ub, 256, 0, stream>>>(h, agg, params, W_diff + 256,
                                         W_out, b_out, (float*)d_out, n);
}